// Round 9
// baseline (213.548 us; speedup 1.0000x reference)
//
#include <hip/hip_runtime.h>
#include <math.h>

// Problem constants (fixed by the reference harness).
constexpr int B = 16;
constexpr int N = 4096;
constexpr int K = 128;

constexpr int ROWS_PER_BLOCK = 128;  // 128 rows x 128 K = 16384 elems/block
constexpr int THREADS = 1024;        // 16 elems/thread: 4 chunks of 4
constexpr int CHUNKS  = 4;
constexpr int WINDOW  = 2;           // rolling lookahead

// Native clang vector types (needed for __builtin_nontemporal_store).
typedef float fx4 __attribute__((ext_vector_type(4)));
typedef int   ix4 __attribute__((ext_vector_type(4)));

// NT-ablation of R7: loads are plain cached loads (streaming data has no
// reuse, but L2/L3-resident lines from the harness restore are served
// without a forced fabric round-trip); store keeps the NT hint (output is
// never re-read). 512 blocks = 2 blocks/CU, 32 waves/CU, whole-batch
// positions in LDS (gather = one ds_read_b128).

struct Chunk {
    ix4 jj;
    fx4 mm, o0, o1, o2;
};

__device__ __forceinline__ void load_chunk(Chunk& c,
                                           const int*   __restrict__ nbr,
                                           const float* __restrict__ mask,
                                           const float* __restrict__ offs,
                                           size_t e0) {
    c.jj = *(const ix4*)(nbr  + e0);
    c.mm = *(const fx4*)(mask + e0);
    c.o0 = *(const fx4*)(offs + e0 * 3);
    c.o1 = *(const fx4*)(offs + e0 * 3 + 4);
    c.o2 = *(const fx4*)(offs + e0 * 3 + 8);
}

__global__ __launch_bounds__(THREADS, 8)
void pairwise_dist_nont(const float* __restrict__ pos,
                        const int*   __restrict__ nbr,
                        const float* __restrict__ mask,
                        const float* __restrict__ cell,
                        const float* __restrict__ offs,
                        float*       __restrict__ out) {
    __shared__ fx4 spos[N];          // 64 KB

    const int tid   = threadIdx.x;
    const int b     = blockIdx.x >> 5;    // 32 blocks per batch
    const int rblk  = blockIdx.x & 31;
    const int nbase = rblk * ROWS_PER_BLOCK;

    // Stage the batch's full positions: 1024 threads x 12 consecutive floats
    // (3x float4), repacked as 4 padded float4 atoms each. Coalesced.
    {
        const fx4* __restrict__ pb4 = (const fx4*)(pos + (size_t)b * N * 3);
        const fx4 r0 = pb4[tid * 3 + 0];
        const fx4 r1 = pb4[tid * 3 + 1];
        const fx4 r2 = pb4[tid * 3 + 2];
        const int a0 = tid * 4;
        spos[a0 + 0] = (fx4){r0.x, r0.y, r0.z, 0.f};
        spos[a0 + 1] = (fx4){r0.w, r1.x, r1.y, 0.f};
        spos[a0 + 2] = (fx4){r1.z, r1.w, r2.x, 0.f};
        spos[a0 + 3] = (fx4){r2.y, r2.z, r2.w, 0.f};
    }

    // Cell matrix: uniform per block -> scalar (s_load) path.
    const float* __restrict__ cb = cell + b * 9;
    const float c00 = cb[0], c01 = cb[1], c02 = cb[2];
    const float c10 = cb[3], c11 = cb[4], c12 = cb[5];
    const float c20 = cb[6], c21 = cb[7], c22 = cb[8];

    const size_t blockElemBase = ((size_t)b * N + nbase) * K;

    // Rolling window: issue WINDOW chunks of loads before first consumption.
    Chunk win[WINDOW];
#pragma unroll
    for (int c = 0; c < WINDOW; ++c)
        load_chunk(win[c], nbr, mask, offs,
                   blockElemBase + (size_t)c * 4096 + (size_t)tid * 4);

    __syncthreads();   // positions ready (after load issue)

#pragma unroll
    for (int c = 0; c < CHUNKS; ++c) {
        const Chunk cur = win[c % WINDOW];

        // Refill the slot we just freed.
        if (c + WINDOW < CHUNKS)
            load_chunk(win[c % WINDOW], nbr, mask, offs,
                       blockElemBase + (size_t)(c + WINDOW) * 4096 +
                       (size_t)tid * 4);

        const int    eLocal = c * 4096 + tid * 4;
        const size_t e0     = blockElemBase + eLocal;
        const int    n      = nbase + (eLocal >> 7);   // row (K=128)
        const fx4    pi     = spos[n];

        const float ox[4] = {cur.o0.x, cur.o0.w, cur.o1.z, cur.o2.y};
        const float oy[4] = {cur.o0.y, cur.o1.x, cur.o1.w, cur.o2.z};
        const float oz[4] = {cur.o0.z, cur.o1.y, cur.o2.x, cur.o2.w};
        const int   j [4] = {cur.jj.x, cur.jj.y, cur.jj.z, cur.jj.w};
        const float m [4] = {cur.mm.x, cur.mm.y, cur.mm.z, cur.mm.w};

        float res[4];
#pragma unroll
        for (int i = 0; i < 4; ++i) {
            const fx4 pj = spos[j[i]];                 // one ds_read_b128
            const float dx = (pj.x - pi.x) + ox[i] * c00 + oy[i] * c10 + oz[i] * c20;
            const float dy = (pj.y - pi.y) + ox[i] * c01 + oy[i] * c11 + oz[i] * c21;
            const float dz = (pj.z - pi.z) + ox[i] * c02 + oy[i] * c12 + oz[i] * c22;
            const float sq = dx * dx + dy * dy + dz * dz;
            res[i] = (m[i] > 0.0f) ? __builtin_amdgcn_sqrtf(sq) : 0.0f;
        }

        const fx4 r = {res[0], res[1], res[2], res[3]};
        __builtin_nontemporal_store(r, (fx4*)(out + e0));
    }
}

extern "C" void kernel_launch(void* const* d_in, const int* in_sizes, int n_in,
                              void* d_out, int out_size, void* d_ws, size_t ws_size,
                              hipStream_t stream) {
    const float* positions     = (const float*)d_in[0]; // [B,N,3]
    const int*   neighbors     = (const int*)  d_in[1]; // [B,N,K]
    const float* neighbor_mask = (const float*)d_in[2]; // [B,N,K]
    const float* cell          = (const float*)d_in[3]; // [B,3,3]
    const float* cell_offsets  = (const float*)d_in[4]; // [B,N,K,3]
    float*       out           = (float*)d_out;         // [B,N,K]

    const int blocks = B * (N / ROWS_PER_BLOCK);        // 16 * 32 = 512

    pairwise_dist_nont<<<blocks, THREADS, 0, stream>>>(
        positions, neighbors, neighbor_mask, cell, cell_offsets, out);
}

// Round 10
// 203.819 us; speedup vs baseline: 1.0477x; 1.0477x over previous
//
#include <hip/hip_runtime.h>
#include <math.h>

// Problem constants (fixed by the reference harness).
constexpr int B = 16;
constexpr int N = 4096;
constexpr int K = 128;

constexpr int ROWS_PER_BLOCK = 128;  // 128 rows x 128 K = 16384 elems/block
constexpr int THREADS = 1024;        // 16 elems/thread: 4 chunks of 4
constexpr int CHUNKS  = 4;
constexpr int WINDOW  = 2;           // rolling lookahead

// Native clang vector types — required by __builtin_nontemporal_*.
typedef float fx4 __attribute__((ext_vector_type(4)));
typedef int   ix4 __attribute__((ext_vector_type(4)));

// Best-known config (R7): 512 blocks = 2 blocks/CU (64 KB LDS each,
// 32 waves/CU) + NT streaming loads/stores + 2-deep register load window.
// Whole-batch positions in LDS; gather = one ds_read_b128.
// NT on the streaming loads is worth ~23% (R8 ablation: 62 -> 76.5 us).

struct Chunk {
    ix4 jj;
    fx4 mm, o0, o1, o2;
};

__device__ __forceinline__ void load_chunk(Chunk& c,
                                           const int*   __restrict__ nbr,
                                           const float* __restrict__ mask,
                                           const float* __restrict__ offs,
                                           size_t e0) {
    c.jj = __builtin_nontemporal_load((const ix4*)(nbr  + e0));
    c.mm = __builtin_nontemporal_load((const fx4*)(mask + e0));
    c.o0 = __builtin_nontemporal_load((const fx4*)(offs + e0 * 3));
    c.o1 = __builtin_nontemporal_load((const fx4*)(offs + e0 * 3 + 4));
    c.o2 = __builtin_nontemporal_load((const fx4*)(offs + e0 * 3 + 8));
}

__global__ __launch_bounds__(THREADS, 8)
void pairwise_dist_tlp(const float* __restrict__ pos,
                       const int*   __restrict__ nbr,
                       const float* __restrict__ mask,
                       const float* __restrict__ cell,
                       const float* __restrict__ offs,
                       float*       __restrict__ out) {
    __shared__ fx4 spos[N];          // 64 KB

    const int tid   = threadIdx.x;
    const int b     = blockIdx.x >> 5;    // 32 blocks per batch
    const int rblk  = blockIdx.x & 31;
    const int nbase = rblk * ROWS_PER_BLOCK;

    // Stage the batch's full positions: 1024 threads x 12 consecutive floats
    // (3x float4), repacked as 4 padded float4 atoms each. Coalesced.
    {
        const fx4* __restrict__ pb4 = (const fx4*)(pos + (size_t)b * N * 3);
        const fx4 r0 = pb4[tid * 3 + 0];
        const fx4 r1 = pb4[tid * 3 + 1];
        const fx4 r2 = pb4[tid * 3 + 2];
        const int a0 = tid * 4;
        spos[a0 + 0] = (fx4){r0.x, r0.y, r0.z, 0.f};
        spos[a0 + 1] = (fx4){r0.w, r1.x, r1.y, 0.f};
        spos[a0 + 2] = (fx4){r1.z, r1.w, r2.x, 0.f};
        spos[a0 + 3] = (fx4){r2.y, r2.z, r2.w, 0.f};
    }

    // Cell matrix: uniform per block -> scalar (s_load) path.
    const float* __restrict__ cb = cell + b * 9;
    const float c00 = cb[0], c01 = cb[1], c02 = cb[2];
    const float c10 = cb[3], c11 = cb[4], c12 = cb[5];
    const float c20 = cb[6], c21 = cb[7], c22 = cb[8];

    const size_t blockElemBase = ((size_t)b * N + nbase) * K;

    // Rolling window: issue WINDOW chunks of loads before first consumption.
    Chunk win[WINDOW];
#pragma unroll
    for (int c = 0; c < WINDOW; ++c)
        load_chunk(win[c], nbr, mask, offs,
                   blockElemBase + (size_t)c * 4096 + (size_t)tid * 4);

    __syncthreads();   // positions ready (after load issue)

#pragma unroll
    for (int c = 0; c < CHUNKS; ++c) {
        const Chunk cur = win[c % WINDOW];

        // Refill the slot we just freed.
        if (c + WINDOW < CHUNKS)
            load_chunk(win[c % WINDOW], nbr, mask, offs,
                       blockElemBase + (size_t)(c + WINDOW) * 4096 +
                       (size_t)tid * 4);

        const int    eLocal = c * 4096 + tid * 4;
        const size_t e0     = blockElemBase + eLocal;
        const int    n      = nbase + (eLocal >> 7);   // row (K=128)
        const fx4    pi     = spos[n];

        const float ox[4] = {cur.o0.x, cur.o0.w, cur.o1.z, cur.o2.y};
        const float oy[4] = {cur.o0.y, cur.o1.x, cur.o1.w, cur.o2.z};
        const float oz[4] = {cur.o0.z, cur.o1.y, cur.o2.x, cur.o2.w};
        const int   j [4] = {cur.jj.x, cur.jj.y, cur.jj.z, cur.jj.w};
        const float m [4] = {cur.mm.x, cur.mm.y, cur.mm.z, cur.mm.w};

        float res[4];
#pragma unroll
        for (int i = 0; i < 4; ++i) {
            const fx4 pj = spos[j[i]];                 // one ds_read_b128
            const float dx = (pj.x - pi.x) + ox[i] * c00 + oy[i] * c10 + oz[i] * c20;
            const float dy = (pj.y - pi.y) + ox[i] * c01 + oy[i] * c11 + oz[i] * c21;
            const float dz = (pj.z - pi.z) + ox[i] * c02 + oy[i] * c12 + oz[i] * c22;
            const float sq = dx * dx + dy * dy + dz * dz;
            res[i] = (m[i] > 0.0f) ? __builtin_amdgcn_sqrtf(sq) : 0.0f;
        }

        const fx4 r = {res[0], res[1], res[2], res[3]};
        __builtin_nontemporal_store(r, (fx4*)(out + e0));
    }
}

extern "C" void kernel_launch(void* const* d_in, const int* in_sizes, int n_in,
                              void* d_out, int out_size, void* d_ws, size_t ws_size,
                              hipStream_t stream) {
    const float* positions     = (const float*)d_in[0]; // [B,N,3]
    const int*   neighbors     = (const int*)  d_in[1]; // [B,N,K]
    const float* neighbor_mask = (const float*)d_in[2]; // [B,N,K]
    const float* cell          = (const float*)d_in[3]; // [B,3,3]
    const float* cell_offsets  = (const float*)d_in[4]; // [B,N,K,3]
    float*       out           = (float*)d_out;         // [B,N,K]

    const int blocks = B * (N / ROWS_PER_BLOCK);        // 16 * 32 = 512

    pairwise_dist_tlp<<<blocks, THREADS, 0, stream>>>(
        positions, neighbors, neighbor_mask, cell, cell_offsets, out);
}